// Round 8
// baseline (215.638 us; speedup 1.0000x reference)
//
#include <hip/hip_runtime.h>

#define N_ITEMS 8192
#define D_IN    1024
#define E_OUT   1024
#define K_TYPES 8
#define OUT_W   (E_OUT + K_TYPES)   // 1032

// ---------------- ws layout ----------------
// int view:
//  [0..7]   (scratch counts, fallback path)   [8..15] scatter cursors
//  [16..24] offsets[9]                        [25]    ntiles
//  [32..174] tile descriptors {ktype,row_start} (<=71 tiles)
//  [256..8448) sorted row indices
// byte view (fast path only):
//  XBF at 34816          : bf16 X   [8192][1024]  (16 MB)
//  WBF at 34816+16 MB    : bf16 W^T [8][1024(e)][1024(d)] (16 MB)
#define XBF_OFF  34816
#define WBF_OFF  (XBF_OFF + 16777216)
#define WS_NEED  ((size_t)WBF_OFF + 16777216)

typedef __attribute__((ext_vector_type(8))) short          bf16x8;
typedef __attribute__((ext_vector_type(8))) unsigned short u16x8;
typedef __attribute__((ext_vector_type(4))) float          f32x4;

__device__ __forceinline__ unsigned short f2bf(float f) {   // RNE
    unsigned int u = __float_as_uint(f);
    return (unsigned short)((u + 0x7FFFu + ((u >> 16) & 1u)) >> 16);
}

__device__ __forceinline__ void gload16(const void* g, void* l) {
    __builtin_amdgcn_global_load_lds(
        (const __attribute__((address_space(1))) unsigned int*)g,
        (__attribute__((address_space(3)))       unsigned int*)l, 16, 0, 0);
}

// ============ fast path ============

// One block: histogram + scan + tile list + zero cursors.
__global__ __launch_bounds__(256) void k_sortmeta(const int* __restrict__ tid,
                                                  int* __restrict__ ws) {
    __shared__ int cnt[K_TYPES];
    const int t = threadIdx.x;
    if (t < K_TYPES) { cnt[t] = 0; ws[8 + t] = 0; }
    __syncthreads();
    int c[K_TYPES];
    #pragma unroll
    for (int k = 0; k < K_TYPES; ++k) c[k] = 0;
    for (int it = 0; it < N_ITEMS / 256; ++it) {
        const int v = tid[it * 256 + t];
        #pragma unroll
        for (int k = 0; k < K_TYPES; ++k) c[k] += (v == k) ? 1 : 0;
    }
    #pragma unroll
    for (int k = 0; k < K_TYPES; ++k) atomicAdd(&cnt[k], c[k]);
    __syncthreads();
    if (t == 0) {
        int off = 0, nt = 0;
        for (int k = 0; k < K_TYPES; ++k) {
            ws[16 + k] = off;
            const int cc = cnt[k];
            for (int r = 0; r < cc; r += 128) {
                ws[32 + 2 * nt] = k;
                ws[33 + 2 * nt] = off + r;
                ++nt;
            }
            off += cc;
        }
        ws[24] = off;
        ws[25] = nt;
    }
}

// X fp32 -> bf16 (1024 blocks); blocks [0,32) also do scatter + one-hot tail.
__global__ __launch_bounds__(256) void k_convX(const float* __restrict__ X,
                                               const int*   __restrict__ tid,
                                               int* __restrict__ ws,
                                               float* __restrict__ out) {
    const int t = threadIdx.x;
    const int b = blockIdx.x;
    unsigned short* Xbf = (unsigned short*)((char*)ws + XBF_OFF);

    const size_t c0 = (size_t)b * 8192 + (size_t)t * 8;
    float4 v[8];
    #pragma unroll
    for (int j = 0; j < 4; ++j) {
        v[2 * j]     = *(const float4*)(X + c0 + (size_t)j * 2048);
        v[2 * j + 1] = *(const float4*)(X + c0 + (size_t)j * 2048 + 4);
    }
    #pragma unroll
    for (int j = 0; j < 4; ++j) {
        u16x8 o;
        o[0] = f2bf(v[2 * j].x);     o[1] = f2bf(v[2 * j].y);
        o[2] = f2bf(v[2 * j].z);     o[3] = f2bf(v[2 * j].w);
        o[4] = f2bf(v[2 * j + 1].x); o[5] = f2bf(v[2 * j + 1].y);
        o[6] = f2bf(v[2 * j + 1].z); o[7] = f2bf(v[2 * j + 1].w);
        *(u16x8*)(Xbf + c0 + (size_t)j * 2048) = o;
    }
    if (b < 32) {   // scatter + one-hot tail
        const int n = b * 256 + t;
        const int v2 = tid[n];
        const int pos = ws[16 + v2] + atomicAdd(&ws[8 + v2], 1);
        ws[256 + pos] = n;
        float* o2 = out + (size_t)n * OUT_W + E_OUT;
        *(float4*)(o2)     = make_float4(v2 == 0 ? 1.f : 0.f, v2 == 1 ? 1.f : 0.f,
                                         v2 == 2 ? 1.f : 0.f, v2 == 3 ? 1.f : 0.f);
        *(float4*)(o2 + 4) = make_float4(v2 == 4 ? 1.f : 0.f, v2 == 5 ? 1.f : 0.f,
                                         v2 == 6 ? 1.f : 0.f, v2 == 7 ? 1.f : 0.f);
    }
}

// W transpose-convert (1024 blocks): two 64x64 tiles per block, loads batched.
__global__ __launch_bounds__(256) void k_convW(const float* __restrict__ W,
                                               int* __restrict__ ws) {
    __shared__ unsigned short T[64][72];
    const int t = threadIdx.x;
    const int b = blockIdx.x;
    unsigned short* Wbf = (unsigned short*)((char*)ws + WBF_OFF);

    const int tbase = b * 2;                 // 0..2046
    const int dl = t >> 2;                   // 0..63 (d-row within tile)
    const int eq = (t & 3) * 16;             // e-offset within tile
    float4 va[2][4];
    int kk[2], dd0[2], ee0[2];
    #pragma unroll
    for (int s = 0; s < 2; ++s) {
        const int tt = tbase + s;            // 0..2047
        kk[s]  = tt >> 8;
        const int rem = tt & 255;
        dd0[s] = (rem >> 4) << 6;
        ee0[s] = (rem & 15) << 6;
        const float* src = W + ((size_t)(kk[s] * 1024 + dd0[s] + dl)) * 1024 + ee0[s] + eq;
        #pragma unroll
        for (int q = 0; q < 4; ++q)
            va[s][q] = *(const float4*)(src + q * 4);
    }
    const int el = t >> 2;
    const int dq = (t & 3) * 16;
    #pragma unroll
    for (int s = 0; s < 2; ++s) {
        if (s) __syncthreads();              // prior tile's reads complete
        #pragma unroll
        for (int q = 0; q < 4; ++q) {
            T[eq + q * 4 + 0][dl] = f2bf(va[s][q].x);
            T[eq + q * 4 + 1][dl] = f2bf(va[s][q].y);
            T[eq + q * 4 + 2][dl] = f2bf(va[s][q].z);
            T[eq + q * 4 + 3][dl] = f2bf(va[s][q].w);
        }
        __syncthreads();
        unsigned short* dst = Wbf + ((size_t)kk[s] << 20)
                            + (size_t)(ee0[s] + el) * 1024 + dd0[s] + dq;
        *(u16x8*)(dst)     = *(const u16x8*)&T[el][dq];
        *(u16x8*)(dst + 8) = *(const u16x8*)&T[el][dq + 8];
    }
}

// Grouped bf16 GEMM: 128x64 tile (BN=64, round-8 change), BK=64, 4 waves,
// global_load_lds staging, mfma_f32_16x16x32_bf16, 4x2 frags/wave,
// fused bias, masked scatter epilogue. Grid (72,16) = 1152 blocks, 24KB LDS.
__global__ __launch_bounds__(256) void k_gemm_bf16(const float* __restrict__ Bias,
                                                   const int* __restrict__ ws,
                                                   float* __restrict__ out) {
    __shared__ unsigned short As[128 * 64];
    __shared__ unsigned short Bs[64 * 64];

    const int tile = blockIdx.x;
    if (tile >= ws[25]) return;
    const int ktype     = ws[32 + 2 * tile];
    const int row_start = ws[33 + 2 * tile];
    const int rows      = min(128, ws[17 + ktype] - row_start);
    const int* __restrict__ sorted = ws + 256 + row_start;
    const int bn0 = blockIdx.y * 64;

    const unsigned short* __restrict__ Xbf =
        (const unsigned short*)((const char*)ws + XBF_OFF);
    const unsigned short* __restrict__ Wbf =
        (const unsigned short*)((const char*)ws + WBF_OFF);

    const int t    = threadIdx.x;
    const int lane = t & 63;
    const int w    = t >> 6;
    const int wr   = w >> 1, wc = w & 1;

    // staging geometry: 1KB issue = 8 rows x 128B; lane -> (row, 16B chunk)
    const int srow = lane >> 3;            // 0..7
    const int skq  = (lane & 7) * 8;       // bf16 element offset in row

    const unsigned short* gA[4];
    unsigned short* lA[4];
    #pragma unroll
    for (int i = 0; i < 4; ++i) {
        const int ar = w * 32 + i * 8 + srow;
        const int cr = sorted[ar < rows ? ar : rows - 1];
        gA[i] = Xbf + (size_t)cr * 1024 + skq;
        lA[i] = As + (w * 32 + i * 8) * 64;
    }
    const unsigned short* gB[2];
    unsigned short* lB[2];
    #pragma unroll
    for (int i = 0; i < 2; ++i) {
        const int er = bn0 + w * 16 + i * 8 + srow;
        gB[i] = Wbf + ((size_t)ktype << 20) + (size_t)er * 1024 + skq;
        lB[i] = Bs + (w * 16 + i * 8) * 64;
    }

    const int frow = lane & 15;
    const int fko  = (lane >> 4) * 8;      // k sub-offset within 32
    const unsigned short* aB  = As + (wr * 64 + frow) * 64 + fko;
    const unsigned short* bBp = Bs + (wc * 32 + frow) * 64 + fko;

    f32x4 acc[4][2];
    #pragma unroll
    for (int m = 0; m < 4; ++m)
        #pragma unroll
        for (int n = 0; n < 2; ++n)
            acc[m][n] = (f32x4){0.f, 0.f, 0.f, 0.f};

    for (int k0 = 0; k0 < D_IN; k0 += 64) {
        #pragma unroll
        for (int i = 0; i < 4; ++i) gload16(gA[i] + k0, lA[i]);
        #pragma unroll
        for (int i = 0; i < 2; ++i) gload16(gB[i] + k0, lB[i]);
        __syncthreads();   // drains vmcnt(0): staged data visible
        bf16x8 af[2][4], bf_[2][2];
        #pragma unroll
        for (int ks = 0; ks < 2; ++ks) {
            #pragma unroll
            for (int m = 0; m < 4; ++m)
                af[ks][m]  = *(const bf16x8*)(aB  + m * 16 * 64 + ks * 32);
            #pragma unroll
            for (int n = 0; n < 2; ++n)
                bf_[ks][n] = *(const bf16x8*)(bBp + n * 16 * 64 + ks * 32);
        }
        #pragma unroll
        for (int ks = 0; ks < 2; ++ks)
            #pragma unroll
            for (int m = 0; m < 4; ++m)
                #pragma unroll
                for (int n = 0; n < 2; ++n)
                    acc[m][n] = __builtin_amdgcn_mfma_f32_16x16x32_bf16(
                        af[ks][m], bf_[ks][n], acc[m][n], 0, 0, 0);
        __syncthreads();   // all reads done before next overwrite
    }

    // epilogue: C frag (row=(l>>4)*4+j, col=l&15), bias fused, masked scatter
    const int col = lane & 15;
    const int rq  = (lane >> 4) * 4;
    float bv[2];
    #pragma unroll
    for (int n = 0; n < 2; ++n)
        bv[n] = Bias[ktype * E_OUT + bn0 + wc * 32 + n * 16 + col];
    #pragma unroll
    for (int m = 0; m < 4; ++m)
        #pragma unroll
        for (int j = 0; j < 4; ++j) {
            const int lr = wr * 64 + m * 16 + rq + j;
            if (lr < rows) {
                float* o = out + (size_t)sorted[lr] * OUT_W + bn0 + wc * 32 + col;
                o[0]  = acc[m][0][j] + bv[0];
                o[16] = acc[m][1][j] + bv[1];
            }
        }
}

// ============ fallback fp32 path (round-1, proven) ============

__global__ void k_init(int* __restrict__ ws) {
    int t = threadIdx.x;
    if (t < K_TYPES) { ws[t] = 0; ws[8 + t] = 0; }
    if (t == 0) ws[25] = 0;
}
__global__ void k_hist(const int* __restrict__ tid, int* __restrict__ ws) {
    int n = blockIdx.x * 256 + threadIdx.x;
    if (n < N_ITEMS) atomicAdd(&ws[tid[n]], 1);
}
__global__ void k_scan(int* __restrict__ ws) {
    if (threadIdx.x != 0 || blockIdx.x != 0) return;
    int off = 0, nt = 0;
    for (int k = 0; k < K_TYPES; ++k) {
        ws[16 + k] = off;
        int c = ws[k];
        for (int r = 0; r < c; r += 128) { ws[32 + 2 * nt] = k; ws[33 + 2 * nt] = off + r; ++nt; }
        off += c;
    }
    ws[24] = off; ws[25] = nt;
}
__global__ void k_scatter(const int* __restrict__ tid, int* __restrict__ ws) {
    int n = blockIdx.x * 256 + threadIdx.x;
    if (n >= N_ITEMS) return;
    int v = tid[n];
    int pos = ws[16 + v] + atomicAdd(&ws[8 + v], 1);
    ws[256 + pos] = n;
}
__global__ void k_tail(const int* __restrict__ tid, float* __restrict__ out) {
    int i = blockIdx.x * 256 + threadIdx.x;
    if (i >= N_ITEMS * K_TYPES) return;
    int n = i >> 3, j = i & 7;
    out[(size_t)n * OUT_W + E_OUT + j] = (tid[n] == j) ? 1.0f : 0.0f;
}
__global__ __launch_bounds__(256) void k_gemm(const float* __restrict__ X,
                                              const float* __restrict__ Wt,
                                              const float* __restrict__ Bias,
                                              const int* __restrict__ ws,
                                              float* __restrict__ out) {
    const int tile = blockIdx.x;
    if (tile >= ws[25]) return;
    const int ktype = ws[32 + 2 * tile];
    const int row_start = ws[33 + 2 * tile];
    const int rows = min(128, ws[17 + ktype] - row_start);
    const int* __restrict__ sorted = ws + 256 + row_start;
    const int bn0 = blockIdx.y * 128;
    __shared__ float As2[16][132];
    __shared__ float Bs2[16][132];
    const int t = threadIdx.x, tx = t & 15, ty = t >> 4;
    const int arow0 = t >> 2, arow1 = arow0 + 64, akq = t & 3;
    const int ra = sorted[(arow0 < rows) ? arow0 : 0];
    const int rb = sorted[(arow1 < rows) ? arow1 : 0];
    const float* xa = X + (size_t)ra * D_IN + akq * 4;
    const float* xb = X + (size_t)rb * D_IN + akq * 4;
    const int bdr = t >> 5, bc = (t & 31) * 4;
    const float* wbase = Wt + ((size_t)ktype * D_IN) * E_OUT + bn0;
    const float* w0 = wbase + (size_t)bdr * E_OUT + bc;
    const float* w1 = wbase + (size_t)(bdr + 8) * E_OUT + bc;
    float acc[8][8];
    #pragma unroll
    for (int i = 0; i < 8; ++i)
        #pragma unroll
        for (int j = 0; j < 8; ++j) acc[i][j] = 0.f;
    for (int k0 = 0; k0 < D_IN; k0 += 16) {
        const float4 a0 = *(const float4*)(xa + k0);
        const float4 a1 = *(const float4*)(xb + k0);
        const float4 b0 = *(const float4*)(w0 + (size_t)k0 * E_OUT);
        const float4 b1 = *(const float4*)(w1 + (size_t)k0 * E_OUT);
        __syncthreads();
        As2[akq * 4 + 0][arow0] = a0.x; As2[akq * 4 + 1][arow0] = a0.y;
        As2[akq * 4 + 2][arow0] = a0.z; As2[akq * 4 + 3][arow0] = a0.w;
        As2[akq * 4 + 0][arow1] = a1.x; As2[akq * 4 + 1][arow1] = a1.y;
        As2[akq * 4 + 2][arow1] = a1.z; As2[akq * 4 + 3][arow1] = a1.w;
        *(float4*)&Bs2[bdr][bc] = b0; *(float4*)&Bs2[bdr + 8][bc] = b1;
        __syncthreads();
        #pragma unroll
        for (int kk = 0; kk < 16; ++kk) {
            const float4 av0 = *(const float4*)&As2[kk][ty * 4];
            const float4 av1 = *(const float4*)&As2[kk][64 + ty * 4];
            const float4 bv0 = *(const float4*)&Bs2[kk][tx * 4];
            const float4 bv1 = *(const float4*)&Bs2[kk][64 + tx * 4];
            const float a[8] = {av0.x, av0.y, av0.z, av0.w, av1.x, av1.y, av1.z, av1.w};
            const float bb[8] = {bv0.x, bv0.y, bv0.z, bv0.w, bv1.x, bv1.y, bv1.z, bv1.w};
            #pragma unroll
            for (int i = 0; i < 8; ++i)
                #pragma unroll
                for (int j = 0; j < 8; ++j) acc[i][j] = fmaf(a[i], bb[j], acc[i][j]);
        }
    }
    const float* bias = Bias + ktype * E_OUT + bn0;
    const float4 bi0 = *(const float4*)&bias[tx * 4];
    const float4 bi1 = *(const float4*)&bias[64 + tx * 4];
    const float bb[8] = {bi0.x, bi0.y, bi0.z, bi0.w, bi1.x, bi1.y, bi1.z, bi1.w};
    #pragma unroll
    for (int i = 0; i < 8; ++i) {
        const int lr = (i >> 2) * 64 + ty * 4 + (i & 3);
        if (lr < rows) {
            float* o = out + (size_t)sorted[lr] * OUT_W + bn0;
            *(float4*)&o[tx * 4] = make_float4(acc[i][0] + bb[0], acc[i][1] + bb[1],
                                               acc[i][2] + bb[2], acc[i][3] + bb[3]);
            *(float4*)&o[64 + tx * 4] = make_float4(acc[i][4] + bb[4], acc[i][5] + bb[5],
                                                    acc[i][6] + bb[6], acc[i][7] + bb[7]);
        }
    }
}

extern "C" void kernel_launch(void* const* d_in, const int* in_sizes, int n_in,
                              void* d_out, int out_size, void* d_ws, size_t ws_size,
                              hipStream_t stream) {
    const float* x   = (const float*)d_in[0];
    const int*   tid = (const int*)d_in[1];
    const float* W   = (const float*)d_in[2];
    const float* b   = (const float*)d_in[3];
    float* out = (float*)d_out;
    int*   ws  = (int*)d_ws;

    if (ws_size >= WS_NEED) {
        k_sortmeta<<<1, 256, 0, stream>>>(tid, ws);
        k_convX<<<1024, 256, 0, stream>>>(x, tid, ws, out);
        k_convW<<<1024, 256, 0, stream>>>(W, ws);
        dim3 grid(72, 16);
        k_gemm_bf16<<<grid, 256, 0, stream>>>(b, ws, out);
    } else {
        k_init<<<1, 64, 0, stream>>>(ws);
        k_hist<<<N_ITEMS / 256, 256, 0, stream>>>(tid, ws);
        k_scan<<<1, 1, 0, stream>>>(ws);
        k_scatter<<<N_ITEMS / 256, 256, 0, stream>>>(tid, ws);
        k_tail<<<(N_ITEMS * K_TYPES) / 256, 256, 0, stream>>>(tid, out);
        dim3 grid(72, 8);
        k_gemm<<<grid, 256, 0, stream>>>(x, W, b, ws, out);
    }
}

// Round 10
// 181.283 us; speedup vs baseline: 1.1895x; 1.1895x over previous
//
#include <hip/hip_runtime.h>

#define N_ITEMS 8192
#define D_IN    1024
#define E_OUT   1024
#define K_TYPES 8
#define OUT_W   (E_OUT + K_TYPES)   // 1032

// ---------------- ws layout ----------------
// int view:
//  [0..7]   (scratch counts, fallback path)   [8..15] scatter cursors
//  [16..24] offsets[9]                        [25]    ntiles
//  [32..174] tile descriptors {ktype,row_start} (<=71 tiles)
//  [256..8448) sorted row indices
// byte view (fast path only):
//  XBF at 34816          : bf16 X   [8192][1024]  (16 MB)
//  WBF at 34816+16 MB    : bf16 W^T [8][1024(e)][1024(d)] (16 MB)
#define XBF_OFF  34816
#define WBF_OFF  (XBF_OFF + 16777216)
#define WS_NEED  ((size_t)WBF_OFF + 16777216)

typedef __attribute__((ext_vector_type(8))) short          bf16x8;
typedef __attribute__((ext_vector_type(8))) unsigned short u16x8;
typedef __attribute__((ext_vector_type(4))) float          f32x4;

__device__ __forceinline__ unsigned short f2bf(float f) {   // RNE
    unsigned int u = __float_as_uint(f);
    return (unsigned short)((u + 0x7FFFu + ((u >> 16) & 1u)) >> 16);
}

__device__ __forceinline__ void gload16(const void* g, void* l) {
    __builtin_amdgcn_global_load_lds(
        (const __attribute__((address_space(1))) unsigned int*)g,
        (__attribute__((address_space(3)))       unsigned int*)l, 16, 0, 0);
}

// ============ fast path ============

// One block: histogram + scan + tile list + zero cursors.
__global__ __launch_bounds__(256) void k_sortmeta(const int* __restrict__ tid,
                                                  int* __restrict__ ws) {
    __shared__ int cnt[K_TYPES];
    const int t = threadIdx.x;
    if (t < K_TYPES) { cnt[t] = 0; ws[8 + t] = 0; }
    __syncthreads();
    int c[K_TYPES];
    #pragma unroll
    for (int k = 0; k < K_TYPES; ++k) c[k] = 0;
    for (int it = 0; it < N_ITEMS / 256; ++it) {
        const int v = tid[it * 256 + t];
        #pragma unroll
        for (int k = 0; k < K_TYPES; ++k) c[k] += (v == k) ? 1 : 0;
    }
    #pragma unroll
    for (int k = 0; k < K_TYPES; ++k) atomicAdd(&cnt[k], c[k]);
    __syncthreads();
    if (t == 0) {
        int off = 0, nt = 0;
        for (int k = 0; k < K_TYPES; ++k) {
            ws[16 + k] = off;
            const int cc = cnt[k];
            for (int r = 0; r < cc; r += 128) {
                ws[32 + 2 * nt] = k;
                ws[33 + 2 * nt] = off + r;
                ++nt;
            }
            off += cc;
        }
        ws[24] = off;
        ws[25] = nt;
    }
}

// X fp32 -> bf16 (1024 blocks); blocks [0,32) also do scatter + one-hot tail.
// Round-9: scatter uses wave-ballot ranking + ONE atomicAdd per type per block
// (was: per-thread contended atomicAdd -- the 51 us serializer).
__global__ __launch_bounds__(256) void k_convX(const float* __restrict__ X,
                                               const int*   __restrict__ tid,
                                               int* __restrict__ ws,
                                               float* __restrict__ out) {
    __shared__ int wcnt[4][K_TYPES];
    __shared__ int wbase[4][K_TYPES];
    const int t = threadIdx.x;
    const int b = blockIdx.x;
    unsigned short* Xbf = (unsigned short*)((char*)ws + XBF_OFF);

    const size_t c0 = (size_t)b * 8192 + (size_t)t * 8;
    float4 v[8];
    #pragma unroll
    for (int j = 0; j < 4; ++j) {
        v[2 * j]     = *(const float4*)(X + c0 + (size_t)j * 2048);
        v[2 * j + 1] = *(const float4*)(X + c0 + (size_t)j * 2048 + 4);
    }
    #pragma unroll
    for (int j = 0; j < 4; ++j) {
        u16x8 o;
        o[0] = f2bf(v[2 * j].x);     o[1] = f2bf(v[2 * j].y);
        o[2] = f2bf(v[2 * j].z);     o[3] = f2bf(v[2 * j].w);
        o[4] = f2bf(v[2 * j + 1].x); o[5] = f2bf(v[2 * j + 1].y);
        o[6] = f2bf(v[2 * j + 1].z); o[7] = f2bf(v[2 * j + 1].w);
        *(u16x8*)(Xbf + c0 + (size_t)j * 2048) = o;
    }
    if (b < 32) {   // scatter (ballot-ranked) + one-hot tail
        const int n    = b * 256 + t;
        const int v2   = tid[n];
        const int lane = t & 63;
        const int wv   = t >> 6;           // 0..3
        int myrank = 0;
        int mycnt  = 0;                    // lane k (<8): count of type k in wave
        #pragma unroll
        for (int k = 0; k < K_TYPES; ++k) {
            const unsigned long long mk = __ballot(v2 == k);
            if (v2 == k)
                myrank = (int)__popcll(mk & ((1ull << lane) - 1ull));
            if (lane == k)
                mycnt = (int)__popcll(mk);
        }
        if (lane < K_TYPES) wcnt[wv][lane] = mycnt;
        __syncthreads();
        if (t < K_TYPES) {
            const int tot = wcnt[0][t] + wcnt[1][t] + wcnt[2][t] + wcnt[3][t];
            int base = ws[16 + t] + atomicAdd(&ws[8 + t], tot);
            #pragma unroll
            for (int q = 0; q < 4; ++q) { wbase[q][t] = base; base += wcnt[q][t]; }
        }
        __syncthreads();
        ws[256 + wbase[wv][v2] + myrank] = n;

        float* o2 = out + (size_t)n * OUT_W + E_OUT;
        *(float4*)(o2)     = make_float4(v2 == 0 ? 1.f : 0.f, v2 == 1 ? 1.f : 0.f,
                                         v2 == 2 ? 1.f : 0.f, v2 == 3 ? 1.f : 0.f);
        *(float4*)(o2 + 4) = make_float4(v2 == 4 ? 1.f : 0.f, v2 == 5 ? 1.f : 0.f,
                                         v2 == 6 ? 1.f : 0.f, v2 == 7 ? 1.f : 0.f);
    }
}

// W transpose-convert (1024 blocks): two 64x64 tiles per block, loads batched.
__global__ __launch_bounds__(256) void k_convW(const float* __restrict__ W,
                                               int* __restrict__ ws) {
    __shared__ unsigned short T[64][72];
    const int t = threadIdx.x;
    const int b = blockIdx.x;
    unsigned short* Wbf = (unsigned short*)((char*)ws + WBF_OFF);

    const int tbase = b * 2;                 // 0..2046
    const int dl = t >> 2;                   // 0..63 (d-row within tile)
    const int eq = (t & 3) * 16;             // e-offset within tile
    float4 va[2][4];
    int kk[2], dd0[2], ee0[2];
    #pragma unroll
    for (int s = 0; s < 2; ++s) {
        const int tt = tbase + s;            // 0..2047
        kk[s]  = tt >> 8;
        const int rem = tt & 255;
        dd0[s] = (rem >> 4) << 6;
        ee0[s] = (rem & 15) << 6;
        const float* src = W + ((size_t)(kk[s] * 1024 + dd0[s] + dl)) * 1024 + ee0[s] + eq;
        #pragma unroll
        for (int q = 0; q < 4; ++q)
            va[s][q] = *(const float4*)(src + q * 4);
    }
    const int el = t >> 2;
    const int dq = (t & 3) * 16;
    #pragma unroll
    for (int s = 0; s < 2; ++s) {
        if (s) __syncthreads();              // prior tile's reads complete
        #pragma unroll
        for (int q = 0; q < 4; ++q) {
            T[eq + q * 4 + 0][dl] = f2bf(va[s][q].x);
            T[eq + q * 4 + 1][dl] = f2bf(va[s][q].y);
            T[eq + q * 4 + 2][dl] = f2bf(va[s][q].z);
            T[eq + q * 4 + 3][dl] = f2bf(va[s][q].w);
        }
        __syncthreads();
        unsigned short* dst = Wbf + ((size_t)kk[s] << 20)
                            + (size_t)(ee0[s] + el) * 1024 + dd0[s] + dq;
        *(u16x8*)(dst)     = *(const u16x8*)&T[el][dq];
        *(u16x8*)(dst + 8) = *(const u16x8*)&T[el][dq + 8];
    }
}

// Grouped bf16 GEMM: 128x64 tile, BK=64, 4 waves, global_load_lds staging,
// mfma_f32_16x16x32_bf16, 4x2 frags/wave, fused bias, masked scatter epilogue.
// Grid (72,16) = 1152 blocks, 24KB LDS. UNCHANGED from round 8 (control).
__global__ __launch_bounds__(256) void k_gemm_bf16(const float* __restrict__ Bias,
                                                   const int* __restrict__ ws,
                                                   float* __restrict__ out) {
    __shared__ unsigned short As[128 * 64];
    __shared__ unsigned short Bs[64 * 64];

    const int tile = blockIdx.x;
    if (tile >= ws[25]) return;
    const int ktype     = ws[32 + 2 * tile];
    const int row_start = ws[33 + 2 * tile];
    const int rows      = min(128, ws[17 + ktype] - row_start);
    const int* __restrict__ sorted = ws + 256 + row_start;
    const int bn0 = blockIdx.y * 64;

    const unsigned short* __restrict__ Xbf =
        (const unsigned short*)((const char*)ws + XBF_OFF);
    const unsigned short* __restrict__ Wbf =
        (const unsigned short*)((const char*)ws + WBF_OFF);

    const int t    = threadIdx.x;
    const int lane = t & 63;
    const int w    = t >> 6;
    const int wr   = w >> 1, wc = w & 1;

    // staging geometry: 1KB issue = 8 rows x 128B; lane -> (row, 16B chunk)
    const int srow = lane >> 3;            // 0..7
    const int skq  = (lane & 7) * 8;       // bf16 element offset in row

    const unsigned short* gA[4];
    unsigned short* lA[4];
    #pragma unroll
    for (int i = 0; i < 4; ++i) {
        const int ar = w * 32 + i * 8 + srow;
        const int cr = sorted[ar < rows ? ar : rows - 1];
        gA[i] = Xbf + (size_t)cr * 1024 + skq;
        lA[i] = As + (w * 32 + i * 8) * 64;
    }
    const unsigned short* gB[2];
    unsigned short* lB[2];
    #pragma unroll
    for (int i = 0; i < 2; ++i) {
        const int er = bn0 + w * 16 + i * 8 + srow;
        gB[i] = Wbf + ((size_t)ktype << 20) + (size_t)er * 1024 + skq;
        lB[i] = Bs + (w * 16 + i * 8) * 64;
    }

    const int frow = lane & 15;
    const int fko  = (lane >> 4) * 8;      // k sub-offset within 32
    const unsigned short* aB  = As + (wr * 64 + frow) * 64 + fko;
    const unsigned short* bBp = Bs + (wc * 32 + frow) * 64 + fko;

    f32x4 acc[4][2];
    #pragma unroll
    for (int m = 0; m < 4; ++m)
        #pragma unroll
        for (int n = 0; n < 2; ++n)
            acc[m][n] = (f32x4){0.f, 0.f, 0.f, 0.f};

    for (int k0 = 0; k0 < D_IN; k0 += 64) {
        #pragma unroll
        for (int i = 0; i < 4; ++i) gload16(gA[i] + k0, lA[i]);
        #pragma unroll
        for (int i = 0; i < 2; ++i) gload16(gB[i] + k0, lB[i]);
        __syncthreads();   // drains vmcnt(0): staged data visible
        bf16x8 af[2][4], bf_[2][2];
        #pragma unroll
        for (int ks = 0; ks < 2; ++ks) {
            #pragma unroll
            for (int m = 0; m < 4; ++m)
                af[ks][m]  = *(const bf16x8*)(aB  + m * 16 * 64 + ks * 32);
            #pragma unroll
            for (int n = 0; n < 2; ++n)
                bf_[ks][n] = *(const bf16x8*)(bBp + n * 16 * 64 + ks * 32);
        }
        #pragma unroll
        for (int ks = 0; ks < 2; ++ks)
            #pragma unroll
            for (int m = 0; m < 4; ++m)
                #pragma unroll
                for (int n = 0; n < 2; ++n)
                    acc[m][n] = __builtin_amdgcn_mfma_f32_16x16x32_bf16(
                        af[ks][m], bf_[ks][n], acc[m][n], 0, 0, 0);
        __syncthreads();   // all reads done before next overwrite
    }

    // epilogue: C frag (row=(l>>4)*4+j, col=l&15), bias fused, masked scatter
    const int col = lane & 15;
    const int rq  = (lane >> 4) * 4;
    float bv[2];
    #pragma unroll
    for (int n = 0; n < 2; ++n)
        bv[n] = Bias[ktype * E_OUT + bn0 + wc * 32 + n * 16 + col];
    #pragma unroll
    for (int m = 0; m < 4; ++m)
        #pragma unroll
        for (int j = 0; j < 4; ++j) {
            const int lr = wr * 64 + m * 16 + rq + j;
            if (lr < rows) {
                float* o = out + (size_t)sorted[lr] * OUT_W + bn0 + wc * 32 + col;
                o[0]  = acc[m][0][j] + bv[0];
                o[16] = acc[m][1][j] + bv[1];
            }
        }
}

// ============ fallback fp32 path (round-1, proven) ============

__global__ void k_init(int* __restrict__ ws) {
    int t = threadIdx.x;
    if (t < K_TYPES) { ws[t] = 0; ws[8 + t] = 0; }
    if (t == 0) ws[25] = 0;
}
__global__ void k_hist(const int* __restrict__ tid, int* __restrict__ ws) {
    int n = blockIdx.x * 256 + threadIdx.x;
    if (n < N_ITEMS) atomicAdd(&ws[tid[n]], 1);
}
__global__ void k_scan(int* __restrict__ ws) {
    if (threadIdx.x != 0 || blockIdx.x != 0) return;
    int off = 0, nt = 0;
    for (int k = 0; k < K_TYPES; ++k) {
        ws[16 + k] = off;
        int c = ws[k];
        for (int r = 0; r < c; r += 128) { ws[32 + 2 * nt] = k; ws[33 + 2 * nt] = off + r; ++nt; }
        off += c;
    }
    ws[24] = off; ws[25] = nt;
}
__global__ void k_scatter(const int* __restrict__ tid, int* __restrict__ ws) {
    int n = blockIdx.x * 256 + threadIdx.x;
    if (n >= N_ITEMS) return;
    int v = tid[n];
    int pos = ws[16 + v] + atomicAdd(&ws[8 + v], 1);
    ws[256 + pos] = n;
}
__global__ void k_tail(const int* __restrict__ tid, float* __restrict__ out) {
    int i = blockIdx.x * 256 + threadIdx.x;
    if (i >= N_ITEMS * K_TYPES) return;
    int n = i >> 3, j = i & 7;
    out[(size_t)n * OUT_W + E_OUT + j] = (tid[n] == j) ? 1.0f : 0.0f;
}
__global__ __launch_bounds__(256) void k_gemm(const float* __restrict__ X,
                                              const float* __restrict__ Wt,
                                              const float* __restrict__ Bias,
                                              const int* __restrict__ ws,
                                              float* __restrict__ out) {
    const int tile = blockIdx.x;
    if (tile >= ws[25]) return;
    const int ktype = ws[32 + 2 * tile];
    const int row_start = ws[33 + 2 * tile];
    const int rows = min(128, ws[17 + ktype] - row_start);
    const int* __restrict__ sorted = ws + 256 + row_start;
    const int bn0 = blockIdx.y * 128;
    __shared__ float As2[16][132];
    __shared__ float Bs2[16][132];
    const int t = threadIdx.x, tx = t & 15, ty = t >> 4;
    const int arow0 = t >> 2, arow1 = arow0 + 64, akq = t & 3;
    const int ra = sorted[(arow0 < rows) ? arow0 : 0];
    const int rb = sorted[(arow1 < rows) ? arow1 : 0];
    const float* xa = X + (size_t)ra * D_IN + akq * 4;
    const float* xb = X + (size_t)rb * D_IN + akq * 4;
    const int bdr = t >> 5, bc = (t & 31) * 4;
    const float* wbase = Wt + ((size_t)ktype * D_IN) * E_OUT + bn0;
    const float* w0 = wbase + (size_t)bdr * E_OUT + bc;
    const float* w1 = wbase + (size_t)(bdr + 8) * E_OUT + bc;
    float acc[8][8];
    #pragma unroll
    for (int i = 0; i < 8; ++i)
        #pragma unroll
        for (int j = 0; j < 8; ++j) acc[i][j] = 0.f;
    for (int k0 = 0; k0 < D_IN; k0 += 16) {
        const float4 a0 = *(const float4*)(xa + k0);
        const float4 a1 = *(const float4*)(xb + k0);
        const float4 b0 = *(const float4*)(w0 + (size_t)k0 * E_OUT);
        const float4 b1 = *(const float4*)(w1 + (size_t)k0 * E_OUT);
        __syncthreads();
        As2[akq * 4 + 0][arow0] = a0.x; As2[akq * 4 + 1][arow0] = a0.y;
        As2[akq * 4 + 2][arow0] = a0.z; As2[akq * 4 + 3][arow0] = a0.w;
        As2[akq * 4 + 0][arow1] = a1.x; As2[akq * 4 + 1][arow1] = a1.y;
        As2[akq * 4 + 2][arow1] = a1.z; As2[akq * 4 + 3][arow1] = a1.w;
        *(float4*)&Bs2[bdr][bc] = b0; *(float4*)&Bs2[bdr + 8][bc] = b1;
        __syncthreads();
        #pragma unroll
        for (int kk = 0; kk < 16; ++kk) {
            const float4 av0 = *(const float4*)&As2[kk][ty * 4];
            const float4 av1 = *(const float4*)&As2[kk][64 + ty * 4];
            const float4 bv0 = *(const float4*)&Bs2[kk][tx * 4];
            const float4 bv1 = *(const float4*)&Bs2[kk][64 + tx * 4];
            const float a[8] = {av0.x, av0.y, av0.z, av0.w, av1.x, av1.y, av1.z, av1.w};
            const float bb[8] = {bv0.x, bv0.y, bv0.z, bv0.w, bv1.x, bv1.y, bv1.z, bv1.w};
            #pragma unroll
            for (int i = 0; i < 8; ++i)
                #pragma unroll
                for (int j = 0; j < 8; ++j) acc[i][j] = fmaf(a[i], bb[j], acc[i][j]);
        }
    }
    const float* bias = Bias + ktype * E_OUT + bn0;
    const float4 bi0 = *(const float4*)&bias[tx * 4];
    const float4 bi1 = *(const float4*)&bias[64 + tx * 4];
    const float bb[8] = {bi0.x, bi0.y, bi0.z, bi0.w, bi1.x, bi1.y, bi1.z, bi1.w};
    #pragma unroll
    for (int i = 0; i < 8; ++i) {
        const int lr = (i >> 2) * 64 + ty * 4 + (i & 3);
        if (lr < rows) {
            float* o = out + (size_t)sorted[lr] * OUT_W + bn0;
            *(float4*)&o[tx * 4] = make_float4(acc[i][0] + bb[0], acc[i][1] + bb[1],
                                               acc[i][2] + bb[2], acc[i][3] + bb[3]);
            *(float4*)&o[64 + tx * 4] = make_float4(acc[i][4] + bb[4], acc[i][5] + bb[5],
                                                    acc[i][6] + bb[6], acc[i][7] + bb[7]);
        }
    }
}

extern "C" void kernel_launch(void* const* d_in, const int* in_sizes, int n_in,
                              void* d_out, int out_size, void* d_ws, size_t ws_size,
                              hipStream_t stream) {
    const float* x   = (const float*)d_in[0];
    const int*   tid = (const int*)d_in[1];
    const float* W   = (const float*)d_in[2];
    const float* b   = (const float*)d_in[3];
    float* out = (float*)d_out;
    int*   ws  = (int*)d_ws;

    if (ws_size >= WS_NEED) {
        k_sortmeta<<<1, 256, 0, stream>>>(tid, ws);
        k_convX<<<1024, 256, 0, stream>>>(x, tid, ws, out);
        k_convW<<<1024, 256, 0, stream>>>(W, ws);
        dim3 grid(72, 16);
        k_gemm_bf16<<<grid, 256, 0, stream>>>(b, ws, out);
    } else {
        k_init<<<1, 64, 0, stream>>>(ws);
        k_hist<<<N_ITEMS / 256, 256, 0, stream>>>(tid, ws);
        k_scan<<<1, 1, 0, stream>>>(ws);
        k_scatter<<<N_ITEMS / 256, 256, 0, stream>>>(tid, ws);
        k_tail<<<(N_ITEMS * K_TYPES) / 256, 256, 0, stream>>>(tid, out);
        dim3 grid(72, 8);
        k_gemm<<<grid, 256, 0, stream>>>(x, W, b, ws, out);
    }
}